// Round 3
// baseline (195.851 us; speedup 1.0000x reference)
//
#include <hip/hip_runtime.h>

#define MAX_L 2048   // max phonemes per batch for LDS cumsum
#define MAX_EPC 8    // max cum elements per thread (L <= 256*8)
#define FPB 128      // frames per block

// R0-verified fused length-regulator (best measured variant, absmax 0.0).
// THIS ROUND IS A MEASUREMENT ROUND: kernel_launch enqueues this kernel 3x
// (it is idempotent), so the dur_us delta vs the R0 baseline (145.6 us)
// equals 2x the kernel's true duration F, which the top-5 rocprof view
// cannot show (all top-5 slots are ~80 us harness poison fills).
__global__ __launch_bounds__(256) void lr_fused_kernel(
        const float* __restrict__ feat,
        const int* __restrict__ dur,
        const int* __restrict__ tlen,
        float* __restrict__ out,
        int BL, int BT, int D) {
    const int T = *tlen;
    const int B = BT / T;
    const int L = BL / B;
    const int vecs = D >> 2;

    __shared__ int sc[MAX_L];
    __shared__ int swsum[4];
    __shared__ int sidx[FPB];

    const long frame_base0 = (long)blockIdx.x * FPB;
    if (frame_base0 >= BT) return;

    const int tid  = threadIdx.x;
    const int lane = tid & 63;
    const int wv   = tid >> 6;

    long fb_ = frame_base0;
    int remaining = (int)((long)BT - frame_base0 < FPB ? (long)BT - frame_base0
                                                       : (long)FPB);

    while (remaining > 0) {
        const int b   = (int)(fb_ / T);
        const int tt0 = (int)(fb_ - (long)b * T);
        const int seg = remaining < (T - tt0) ? remaining : (T - tt0);

        // ---- cumsum of batch b's duration row into sc ----
        __syncthreads();  // protect sc/sidx reuse across segments
        const int epc  = (L + blockDim.x - 1) / blockDim.x;
        const int base = tid * epc;
        const int* __restrict__ drow = dur + (size_t)b * L;
        int local[MAX_EPC];
        int run = 0;
#pragma unroll
        for (int e = 0; e < MAX_EPC; ++e) {
            int v = 0;
            if (e < epc && base + e < L) v = drow[base + e];
            run += v;
            local[e] = run;
        }
        int wsum = run;
#pragma unroll
        for (int off = 1; off < 64; off <<= 1) {
            int up = __shfl_up(wsum, off, 64);
            if (lane >= off) wsum += up;
        }
        if (lane == 63) swsum[wv] = wsum;
        __syncthreads();
        int wprefix = 0;
        for (int w = 0; w < wv; ++w) wprefix += swsum[w];
        const int chunk_prefix = wprefix + wsum - run;
#pragma unroll
        for (int e = 0; e < MAX_EPC; ++e)
            if (e < epc && base + e < L) sc[base + e] = chunk_prefix + local[e];
        __syncthreads();

        const int total = sc[L - 1];

        // ---- searchsorted(side='right') for this segment's frames ----
        if (tid < seg) {
            const int t = tt0 + tid;
            int p = -1;
            if (t < total) {
                int lo = 0, hi = L - 1;
                while (lo < hi) {
                    const int mid = (lo + hi) >> 1;
                    if (sc[mid] > t) hi = mid;
                    else             lo = mid + 1;
                }
                p = lo;
            }
            sidx[tid] = p;
        }
        __syncthreads();

        // ---- copy ----
        if (seg == FPB && vecs == 64) {
            // Fast path (D == 256, full segment): wave wv owns 32 contiguous
            // frames; row cached in one float4/lane, reloaded on index change.
            const float4* __restrict__ fbp =
                (const float4*)feat + (size_t)b * L * 64;
            float4* __restrict__ op =
                (float4*)out + ((size_t)fb_ + (size_t)wv * 32) * 64 + lane;
            const int si = sidx[wv * 32 + (lane & 31)];
            int prev = -2;
            float4 v = make_float4(0.f, 0.f, 0.f, 0.f);
#pragma unroll
            for (int j = 0; j < 32; ++j) {
                const int p = __builtin_amdgcn_readlane(si, j);  // uniform
                if (p != prev) {                                  // scalar branch
                    v = (p >= 0) ? fbp[(size_t)p * 64 + lane]
                                 : make_float4(0.f, 0.f, 0.f, 0.f);
                    prev = p;
                }
                op[(size_t)j * 64] = v;   // back-to-back 1 KiB wave stores
            }
        } else {
            // Generic fallback: wave-strided frames, lane-strided float4s.
            const float4* __restrict__ fbp =
                (const float4*)feat + (size_t)b * L * vecs;
            const float4 z = make_float4(0.f, 0.f, 0.f, 0.f);
            for (int f = wv; f < seg; f += 4) {
                const int p = sidx[f];
                float4* __restrict__ orow = (float4*)out + ((size_t)fb_ + f) * vecs;
                if (p >= 0) {
                    const float4* __restrict__ irow = fbp + (size_t)p * vecs;
                    for (int i = lane; i < vecs; i += 64) orow[i] = irow[i];
                } else {
                    for (int i = lane; i < vecs; i += 64) orow[i] = z;
                }
            }
        }

        fb_ += seg;
        remaining -= seg;
    }
}

extern "C" void kernel_launch(void* const* d_in, const int* in_sizes, int n_in,
                              void* d_out, int out_size, void* d_ws, size_t ws_size,
                              hipStream_t stream) {
    const float* feat = (const float*)d_in[0];   // [B, L, D] fp32
    const int*   dur  = (const int*)d_in[1];     // [B, L] int32
    const int*   tlen = (const int*)d_in[2];     // scalar target_length (device)

    const int BL = in_sizes[1];                  // B*L
    const int D  = in_sizes[0] / in_sizes[1];    // feature dim
    const int BT = out_size / D;                 // B*T total frames

    const int grid = (BT + FPB - 1) / FPB;       // 1024 blocks for 16x8192

    // MEASUREMENT: 3 idempotent launches. dur_us - baseline(145.6) ~= 2F.
    lr_fused_kernel<<<grid, 256, 0, stream>>>(feat, dur, tlen, (float*)d_out,
                                              BL, BT, D);
    lr_fused_kernel<<<grid, 256, 0, stream>>>(feat, dur, tlen, (float*)d_out,
                                              BL, BT, D);
    lr_fused_kernel<<<grid, 256, 0, stream>>>(feat, dur, tlen, (float*)d_out,
                                              BL, BT, D);
}

// Round 4
// 151.935 us; speedup vs baseline: 1.2890x; 1.2890x over previous
//
#include <hip/hip_runtime.h>

#define MAX_L 2048   // max phonemes per batch for LDS cumsum
#define MAX_EPC 8    // max cum elements per thread (L <= 256*8)
#define FPB 128      // frames per block

typedef float f32x4 __attribute__((ext_vector_type(4)));

// Fused length-regulator (R0-verified structure, F ~= 25.1 us measured via
// the R3 3x-launch experiment; write floor 20.6 us at 6.5 TB/s).
// Change vs R0: output stores use __builtin_nontemporal_store (MUBUF `nt`)
// -- the 134 MB output stream is write-once, never re-read by this kernel,
// so L2 allocation for it is pure overhead.
__global__ __launch_bounds__(256) void lr_fused_kernel(
        const float* __restrict__ feat,
        const int* __restrict__ dur,
        const int* __restrict__ tlen,
        float* __restrict__ out,
        int BL, int BT, int D) {
    const int T = *tlen;
    const int B = BT / T;
    const int L = BL / B;
    const int vecs = D >> 2;

    __shared__ int sc[MAX_L];
    __shared__ int swsum[4];
    __shared__ int sidx[FPB];

    const long frame_base0 = (long)blockIdx.x * FPB;
    if (frame_base0 >= BT) return;

    const int tid  = threadIdx.x;
    const int lane = tid & 63;
    const int wv   = tid >> 6;

    long fb_ = frame_base0;
    int remaining = (int)((long)BT - frame_base0 < FPB ? (long)BT - frame_base0
                                                       : (long)FPB);

    while (remaining > 0) {
        const int b   = (int)(fb_ / T);
        const int tt0 = (int)(fb_ - (long)b * T);
        const int seg = remaining < (T - tt0) ? remaining : (T - tt0);

        // ---- cumsum of batch b's duration row into sc ----
        __syncthreads();  // protect sc/sidx reuse across segments
        const int epc  = (L + blockDim.x - 1) / blockDim.x;
        const int base = tid * epc;
        const int* __restrict__ drow = dur + (size_t)b * L;
        int local[MAX_EPC];
        int run = 0;
#pragma unroll
        for (int e = 0; e < MAX_EPC; ++e) {
            int v = 0;
            if (e < epc && base + e < L) v = drow[base + e];
            run += v;
            local[e] = run;
        }
        int wsum = run;
#pragma unroll
        for (int off = 1; off < 64; off <<= 1) {
            int up = __shfl_up(wsum, off, 64);
            if (lane >= off) wsum += up;
        }
        if (lane == 63) swsum[wv] = wsum;
        __syncthreads();
        int wprefix = 0;
        for (int w = 0; w < wv; ++w) wprefix += swsum[w];
        const int chunk_prefix = wprefix + wsum - run;
#pragma unroll
        for (int e = 0; e < MAX_EPC; ++e)
            if (e < epc && base + e < L) sc[base + e] = chunk_prefix + local[e];
        __syncthreads();

        const int total = sc[L - 1];

        // ---- searchsorted(side='right') for this segment's frames ----
        if (tid < seg) {
            const int t = tt0 + tid;
            int p = -1;
            if (t < total) {
                int lo = 0, hi = L - 1;
                while (lo < hi) {
                    const int mid = (lo + hi) >> 1;
                    if (sc[mid] > t) hi = mid;
                    else             lo = mid + 1;
                }
                p = lo;
            }
            sidx[tid] = p;
        }
        __syncthreads();

        // ---- copy ----
        if (seg == FPB && vecs == 64) {
            // Fast path (D == 256, full segment): wave wv owns 32 contiguous
            // frames; row cached in one f32x4/lane, reloaded on index change
            // (scalar branch via readlane). Steady state: back-to-back 1 KiB
            // nontemporal wave stores.
            const f32x4* __restrict__ fbp =
                (const f32x4*)feat + (size_t)b * L * 64;
            f32x4* __restrict__ op =
                (f32x4*)out + ((size_t)fb_ + (size_t)wv * 32) * 64 + lane;
            const int si = sidx[wv * 32 + (lane & 31)];
            int prev = -2;
            f32x4 v = (f32x4)(0.f);
#pragma unroll
            for (int j = 0; j < 32; ++j) {
                const int p = __builtin_amdgcn_readlane(si, j);  // uniform
                if (p != prev) {                                  // scalar branch
                    v = (p >= 0) ? fbp[(size_t)p * 64 + lane]
                                 : (f32x4)(0.f);
                    prev = p;
                }
                __builtin_nontemporal_store(v, op + (size_t)j * 64);
            }
        } else {
            // Generic fallback: wave-strided frames, lane-strided f32x4s.
            const f32x4* __restrict__ fbp =
                (const f32x4*)feat + (size_t)b * L * vecs;
            const f32x4 z = (f32x4)(0.f);
            for (int f = wv; f < seg; f += 4) {
                const int p = sidx[f];
                f32x4* __restrict__ orow = (f32x4*)out + ((size_t)fb_ + f) * vecs;
                if (p >= 0) {
                    const f32x4* __restrict__ irow = fbp + (size_t)p * vecs;
                    for (int i = lane; i < vecs; i += 64)
                        __builtin_nontemporal_store(irow[i], orow + i);
                } else {
                    for (int i = lane; i < vecs; i += 64)
                        __builtin_nontemporal_store(z, orow + i);
                }
            }
        }

        fb_ += seg;
        remaining -= seg;
    }
}

extern "C" void kernel_launch(void* const* d_in, const int* in_sizes, int n_in,
                              void* d_out, int out_size, void* d_ws, size_t ws_size,
                              hipStream_t stream) {
    const float* feat = (const float*)d_in[0];   // [B, L, D] fp32
    const int*   dur  = (const int*)d_in[1];     // [B, L] int32
    const int*   tlen = (const int*)d_in[2];     // scalar target_length (device)

    const int BL = in_sizes[1];                  // B*L
    const int D  = in_sizes[0] / in_sizes[1];    // feature dim
    const int BT = out_size / D;                 // B*T total frames

    const int grid = (BT + FPB - 1) / FPB;       // 1024 blocks for 16x8192
    lr_fused_kernel<<<grid, 256, 0, stream>>>(feat, dur, tlen, (float*)d_out,
                                              BL, BT, D);
}

// Round 5
// 145.952 us; speedup vs baseline: 1.3419x; 1.0410x over previous
//
#include <hip/hip_runtime.h>

#define MAX_L 2048   // max phonemes per batch for LDS cumsum
#define MAX_EPC 8    // max cum elements per thread (L <= 256*8)
#define FPB 128      // frames per block

// Fused length-regulator, run-length store streaming. R0-verified BEST variant
// (144.9/145.6 us), restored verbatim after the R4 nt-store experiment came
// back neutral-negative.
//
// Session measurement summary (R3 3x-launch experiment):
//   kernel F ~= 25.1 us vs 20.6 us write floor (134 MB @ 6.5 TB/s fill rate)
//   -> ~82% of achievable write roofline; remaining ~120 us of dur_us is
//   harness-fixed poison-fill/restore traffic (512 MiB fills @ 80-87 us,
//   top-5 of every rocprof capture).
//
// One 256-thread block per 128 output frames:
//   1) block computes its batch's duration cumsum in LDS (shuffle scan)
//   2) 128 threads binary-search in LDS -> sidx[128] (phoneme idx, -1 = pad)
//   3) each wave copies 32 CONTIGUOUS frames; the source row is held in
//      registers and reloaded only when the phoneme index changes (scalar
//      branch via readlane), so steady state is back-to-back coalesced
//      1 KiB stores with no load dependency — memset-shaped.
__global__ __launch_bounds__(256) void lr_fused_kernel(
        const float* __restrict__ feat,
        const int* __restrict__ dur,
        const int* __restrict__ tlen,
        float* __restrict__ out,
        int BL, int BT, int D) {
    const int T = *tlen;
    const int B = BT / T;
    const int L = BL / B;
    const int vecs = D >> 2;

    __shared__ int sc[MAX_L];
    __shared__ int swsum[4];
    __shared__ int sidx[FPB];

    const long frame_base0 = (long)blockIdx.x * FPB;
    if (frame_base0 >= BT) return;

    const int tid  = threadIdx.x;
    const int lane = tid & 63;
    const int wv   = tid >> 6;

    long fb_ = frame_base0;
    int remaining = (int)((long)BT - frame_base0 < FPB ? (long)BT - frame_base0
                                                       : (long)FPB);

    // Segment loop (block-uniform): one iteration in the common case
    // (T % FPB == 0); handles batch-straddling blocks correctly otherwise.
    while (remaining > 0) {
        const int b   = (int)(fb_ / T);
        const int tt0 = (int)(fb_ - (long)b * T);
        const int seg = remaining < (T - tt0) ? remaining : (T - tt0);

        // ---- cumsum of batch b's duration row into sc ----
        __syncthreads();  // protect sc/sidx reuse across segments
        const int epc  = (L + blockDim.x - 1) / blockDim.x;
        const int base = tid * epc;
        const int* __restrict__ drow = dur + (size_t)b * L;
        int local[MAX_EPC];
        int run = 0;
#pragma unroll
        for (int e = 0; e < MAX_EPC; ++e) {
            int v = 0;
            if (e < epc && base + e < L) v = drow[base + e];
            run += v;
            local[e] = run;
        }
        int wsum = run;
#pragma unroll
        for (int off = 1; off < 64; off <<= 1) {
            int up = __shfl_up(wsum, off, 64);
            if (lane >= off) wsum += up;
        }
        if (lane == 63) swsum[wv] = wsum;
        __syncthreads();
        int wprefix = 0;
        for (int w = 0; w < wv; ++w) wprefix += swsum[w];
        const int chunk_prefix = wprefix + wsum - run;
#pragma unroll
        for (int e = 0; e < MAX_EPC; ++e)
            if (e < epc && base + e < L) sc[base + e] = chunk_prefix + local[e];
        __syncthreads();

        const int total = sc[L - 1];

        // ---- searchsorted(side='right') for this segment's frames ----
        if (tid < seg) {
            const int t = tt0 + tid;
            int p = -1;
            if (t < total) {
                int lo = 0, hi = L - 1;
                while (lo < hi) {
                    const int mid = (lo + hi) >> 1;
                    if (sc[mid] > t) hi = mid;
                    else             lo = mid + 1;
                }
                p = lo;
            }
            sidx[tid] = p;
        }
        __syncthreads();

        // ---- copy ----
        if (seg == FPB && vecs == 64) {
            // Fast path (D == 256, full segment): wave wv owns 32 contiguous
            // frames. Row index made scalar via readlane; row data cached in
            // one float4/lane, reloaded only on index change (~2x per 32).
            const float4* __restrict__ fbp =
                (const float4*)feat + (size_t)b * L * 64;
            float4* __restrict__ op =
                (float4*)out + ((size_t)fb_ + (size_t)wv * 32) * 64 + lane;
            const int si = sidx[wv * 32 + (lane & 31)];  // lane j holds sidx[wv*32+j]
            int prev = -2;
            float4 v = make_float4(0.f, 0.f, 0.f, 0.f);
#pragma unroll
            for (int j = 0; j < 32; ++j) {
                const int p = __builtin_amdgcn_readlane(si, j);  // uniform (SGPR)
                if (p != prev) {                                  // scalar branch
                    v = (p >= 0) ? fbp[(size_t)p * 64 + lane]
                                 : make_float4(0.f, 0.f, 0.f, 0.f);
                    prev = p;
                }
                op[(size_t)j * 64] = v;   // back-to-back 1 KiB wave stores
            }
        } else {
            // Generic fallback: wave-strided frames, lane-strided float4s.
            const float4* __restrict__ fbp =
                (const float4*)feat + (size_t)b * L * vecs;
            const float4 z = make_float4(0.f, 0.f, 0.f, 0.f);
            for (int f = wv; f < seg; f += 4) {
                const int p = sidx[f];
                float4* __restrict__ orow = (float4*)out + ((size_t)fb_ + f) * vecs;
                if (p >= 0) {
                    const float4* __restrict__ irow = fbp + (size_t)p * vecs;
                    for (int i = lane; i < vecs; i += 64) orow[i] = irow[i];
                } else {
                    for (int i = lane; i < vecs; i += 64) orow[i] = z;
                }
            }
        }

        fb_ += seg;
        remaining -= seg;
    }
}

extern "C" void kernel_launch(void* const* d_in, const int* in_sizes, int n_in,
                              void* d_out, int out_size, void* d_ws, size_t ws_size,
                              hipStream_t stream) {
    const float* feat = (const float*)d_in[0];   // [B, L, D] fp32
    const int*   dur  = (const int*)d_in[1];     // [B, L] int32
    const int*   tlen = (const int*)d_in[2];     // scalar target_length (device)

    const int BL = in_sizes[1];                  // B*L
    const int D  = in_sizes[0] / in_sizes[1];    // feature dim
    const int BT = out_size / D;                 // B*T total frames

    const int grid = (BT + FPB - 1) / FPB;       // 1024 blocks for 16x8192
    lr_fused_kernel<<<grid, 256, 0, stream>>>(feat, dur, tlen, (float*)d_out,
                                              BL, BT, D);
}